// Round 4
// baseline (3051.427 us; speedup 1.0000x reference)
//
#include <hip/hip_runtime.h>

// ---------------------------------------------------------------------------
// TAGCN node regression: 3 TAGConv layers (K=4) + linear head, fp32.
// CSR-by-dst built once per launch (rank from the degree atomic -> fill has
// no atomics). Propagation fused with matmul accumulation. R4: F=64 fused
// kernel squeezed to exactly 20480 B LDS (8 blocks/CU, 100% waves) via
// XOR-swizzled unpadded t-tile + two-phase W reuse in the FIRST variant.
// ---------------------------------------------------------------------------

typedef unsigned long long u64;

// one 64-bit atomic per edge: [count:16 | sum_w Q16.32 fixed point:48]
// old count = this edge's rank within its dst bucket -> CSR slot, no 2nd atomic
__global__ void degcount_k(const int* __restrict__ dst, const float* __restrict__ w,
                           u64* __restrict__ pack, int* __restrict__ rank, int E) {
  int e = blockIdx.x * blockDim.x + threadIdx.x;
  if (e >= E) return;
  int d = dst[e];
  u64 v = ((u64)1 << 48) | (u64)((double)w[e] * 4294967296.0);
  u64 old = atomicAdd(&pack[d], v);
  rank[e] = (int)(old >> 48);
}

// scan (256/block) fused with degree decode -> dinv
__global__ void scan_blocks(const u64* __restrict__ pack, float* __restrict__ dinv,
                            int* __restrict__ ptr, int* __restrict__ bsum, int n) {
  __shared__ int s[256];
  int tid = threadIdx.x;
  int i = blockIdx.x * 256 + tid;
  int v = 0;
  if (i < n) {
    u64 p = pack[i];
    v = (int)(p >> 48);
    float d = (float)((double)(p & 0xFFFFFFFFFFFFULL) * (1.0 / 4294967296.0));
    dinv[i] = (d > 0.f) ? rsqrtf(fmaxf(d, 1e-30f)) : 0.f;
  }
  s[tid] = v;
  __syncthreads();
#pragma unroll
  for (int off = 1; off < 256; off <<= 1) {
    int t = (tid >= off) ? s[tid - off] : 0;
    __syncthreads();
    s[tid] += t;
    __syncthreads();
  }
  if (i < n) ptr[i] = s[tid] - v;
  if (tid == 255) bsum[blockIdx.x] = s[255];
}

__global__ void scan_sums(int* __restrict__ bsum, int nb) {
  __shared__ int s[512];
  int tid = threadIdx.x;
  int v = (tid < nb) ? bsum[tid] : 0;
  s[tid] = v;
  __syncthreads();
#pragma unroll
  for (int off = 1; off < 512; off <<= 1) {
    int t = (tid >= off) ? s[tid - off] : 0;
    __syncthreads();
    s[tid] += t;
    __syncthreads();
  }
  if (tid < nb) bsum[tid] = s[tid] - v;
}

__global__ void scan_add(int* __restrict__ ptr, const int* __restrict__ bsum, int n, int E) {
  int i = blockIdx.x * blockDim.x + threadIdx.x;
  if (i < n) ptr[i] += bsum[i >> 8];
  if (i == 0) ptr[n] = E;
}

// scatter edges into CSR slots (atomic-free); payload = {src, folded norm}
__global__ void fill_k(const int* __restrict__ src, const int* __restrict__ dst,
                       const float* __restrict__ w, const float* __restrict__ dinv,
                       const int* __restrict__ ptr, const int* __restrict__ rank,
                       int2* __restrict__ ep, int E) {
  int e = blockIdx.x * blockDim.x + threadIdx.x;
  if (e >= E) return;
  int s = src[e], d = dst[e];
  float nv = dinv[s] * w[e] * dinv[d];
  int pos = ptr[d] + rank[e];
  ep[pos] = make_int2(s, __float_as_int(nv));
}

// gather t[f4] = sum_e w_e * hin[src_e][f4]
template <int F4>
__device__ __forceinline__ float4 gather(const int* __restrict__ ptr, const int2* __restrict__ ep,
                                         const float4* __restrict__ hin, int node, int f4) {
  int e0 = ptr[node], e1 = ptr[node + 1];
  float4 a = make_float4(0.f, 0.f, 0.f, 0.f);
  int e = e0;
  if ((e & 1) && e < e1) {
    int2 p = ep[e];
    float w0 = __int_as_float(p.y);
    float4 h = hin[(size_t)p.x * F4 + f4];
    a.x += w0 * h.x; a.y += w0 * h.y; a.z += w0 * h.z; a.w += w0 * h.w;
    ++e;
  }
  for (; e + 1 < e1; e += 2) {
    int4 p = *(const int4*)(ep + e);  // 2 edges, 16B aligned
    float w0 = __int_as_float(p.y), w1 = __int_as_float(p.w);
    float4 h0 = hin[(size_t)p.x * F4 + f4];
    float4 h1 = hin[(size_t)p.z * F4 + f4];
    a.x += w0 * h0.x; a.y += w0 * h0.y; a.z += w0 * h0.z; a.w += w0 * h0.w;
    a.x += w1 * h1.x; a.y += w1 * h1.y; a.z += w1 * h1.z; a.w += w1 * h1.w;
  }
  if (e < e1) {
    int2 p = ep[e];
    float w0 = __int_as_float(p.y);
    float4 h = hin[(size_t)p.x * F4 + f4];
    a.x += w0 * h.x; a.y += w0 * h.y; a.z += w0 * h.z; a.w += w0 * h.w;
  }
  return a;
}

// ---------- fused prop + matmul, F=64 (16 lanes/node, 16 nodes/block) ----------
// LDS = 16K W + 4K XOR-swizzled t tile = 20480 B exactly -> 8 blocks/CU.
// FIRST: two-phase, W buffer reloaded with W0 for the own-term pass.
template <bool FIRST, bool LAST, bool HEAD>
__launch_bounds__(256, 8)
__global__ void ptag64_k(const int* __restrict__ ptr, const int2* __restrict__ ep,
                         const float4* __restrict__ hin, float4* __restrict__ hout,
                         const float4* __restrict__ Wk4, const float4* __restrict__ W04,
                         float4* __restrict__ acc4, const float4* __restrict__ bias4,
                         const float* __restrict__ Wout, const float* __restrict__ bout,
                         float* __restrict__ outv, int n) {
  __shared__ float4 Wl[1024];  // 64x64 weight (reused for W0 in FIRST phase B)
  __shared__ float4 tl4[256];  // t tile, slot = ln*16 + (j4^ln)  (bank-clean)
  int tid = threadIdx.x;
  for (int i = tid; i < 1024; i += 256) Wl[i] = Wk4[i];
  int gid = blockIdx.x * 256 + tid;
  int node = gid >> 4, j4 = gid & 15, ln = tid >> 4;

  float4 t = make_float4(0.f, 0.f, 0.f, 0.f);
  if (node < n) {
    t = gather<16>(ptr, ep, hin, node, j4);
    if (!LAST) hout[(size_t)node * 16 + j4] = t;
  }
  tl4[ln * 16 + (j4 ^ ln)] = t;
  __syncthreads();

  float4 a = make_float4(0.f, 0.f, 0.f, 0.f);
  if (!FIRST && node < n) a = acc4[(size_t)node * 16 + j4];
#pragma unroll
  for (int q = 0; q < 16; ++q) {
    float4 tv = tl4[ln * 16 + (q ^ ln)];  // = t of lane q in this node group
    float4 w0 = Wl[(4 * q + 0) * 16 + j4];
    float4 w1 = Wl[(4 * q + 1) * 16 + j4];
    float4 w2 = Wl[(4 * q + 2) * 16 + j4];
    float4 w3 = Wl[(4 * q + 3) * 16 + j4];
    a.x = fmaf(tv.x, w0.x, a.x); a.y = fmaf(tv.x, w0.y, a.y);
    a.z = fmaf(tv.x, w0.z, a.z); a.w = fmaf(tv.x, w0.w, a.w);
    a.x = fmaf(tv.y, w1.x, a.x); a.y = fmaf(tv.y, w1.y, a.y);
    a.z = fmaf(tv.y, w1.z, a.z); a.w = fmaf(tv.y, w1.w, a.w);
    a.x = fmaf(tv.z, w2.x, a.x); a.y = fmaf(tv.z, w2.y, a.y);
    a.z = fmaf(tv.z, w2.z, a.z); a.w = fmaf(tv.z, w2.w, a.w);
    a.x = fmaf(tv.w, w3.x, a.x); a.y = fmaf(tv.w, w3.y, a.y);
    a.z = fmaf(tv.w, w3.z, a.z); a.w = fmaf(tv.w, w3.w, a.w);
  }
  if (FIRST) {  // phase B: own-term h0 @ W0, same LDS buffers
    __syncthreads();  // everyone done reading Wl/tl4
    for (int i = tid; i < 1024; i += 256) Wl[i] = W04[i];
    float4 own = (node < n) ? hin[(size_t)node * 16 + j4] : make_float4(0.f, 0.f, 0.f, 0.f);
    tl4[ln * 16 + (j4 ^ ln)] = own;
    __syncthreads();
#pragma unroll
    for (int q = 0; q < 16; ++q) {
      float4 tv = tl4[ln * 16 + (q ^ ln)];
      float4 w0 = Wl[(4 * q + 0) * 16 + j4];
      float4 w1 = Wl[(4 * q + 1) * 16 + j4];
      float4 w2 = Wl[(4 * q + 2) * 16 + j4];
      float4 w3 = Wl[(4 * q + 3) * 16 + j4];
      a.x = fmaf(tv.x, w0.x, a.x); a.y = fmaf(tv.x, w0.y, a.y);
      a.z = fmaf(tv.x, w0.z, a.z); a.w = fmaf(tv.x, w0.w, a.w);
      a.x = fmaf(tv.y, w1.x, a.x); a.y = fmaf(tv.y, w1.y, a.y);
      a.z = fmaf(tv.y, w1.z, a.z); a.w = fmaf(tv.y, w1.w, a.w);
      a.x = fmaf(tv.z, w2.x, a.x); a.y = fmaf(tv.z, w2.y, a.y);
      a.z = fmaf(tv.z, w2.z, a.z); a.w = fmaf(tv.z, w2.w, a.w);
      a.x = fmaf(tv.w, w3.x, a.x); a.y = fmaf(tv.w, w3.y, a.y);
      a.z = fmaf(tv.w, w3.z, a.z); a.w = fmaf(tv.w, w3.w, a.w);
    }
  }
  if (node >= n) return;  // no barriers below

  if (LAST) {
    float4 b = bias4[j4];
    a.x += b.x; a.y += b.y; a.z += b.z; a.w += b.w;
    a.x = (a.x >= 0.f) ? a.x : 0.01f * a.x;
    a.y = (a.y >= 0.f) ? a.y : 0.01f * a.y;
    a.z = (a.z >= 0.f) ? a.z : 0.01f * a.z;
    a.w = (a.w >= 0.f) ? a.w : 0.01f * a.w;
    if (HEAD) {
      float v = a.x * Wout[4 * j4] + a.y * Wout[4 * j4 + 1] +
                a.z * Wout[4 * j4 + 2] + a.w * Wout[4 * j4 + 3];
      v += __shfl_down(v, 8, 16);
      v += __shfl_down(v, 4, 16);
      v += __shfl_down(v, 2, 16);
      v += __shfl_down(v, 1, 16);
      if (j4 == 0) outv[node] = v + bout[0];
    } else {
      hout[(size_t)node * 16 + j4] = a;  // activated layer output
    }
  } else {
    acc4[(size_t)node * 16 + j4] = a;
  }
}

// ---------- fused prop + matmul, layer 1: F_in=16 (4 lanes/node, 64 nodes/block) ----------
template <bool FIRST, bool LAST>
__launch_bounds__(256)
__global__ void ptag16_k(const int* __restrict__ ptr, const int2* __restrict__ ep,
                         const float4* __restrict__ hin, float4* __restrict__ hout,
                         const float4* __restrict__ Wk4, const float4* __restrict__ W04,
                         float4* __restrict__ acc4, const float4* __restrict__ bias4,
                         float4* __restrict__ outbuf, int n) {
  __shared__ float4 Wl[256];               // 16x64 W_k
  __shared__ float4 W0l[FIRST ? 256 : 1];  // 16x64 W_0
  __shared__ float4 tl4[64 * 5];           // t tile, stride 5 float4
  const float* tl = (const float*)tl4;
  int tid = threadIdx.x;
  Wl[tid] = Wk4[tid];
  if (FIRST) W0l[tid] = W04[tid];
  int gid = blockIdx.x * 256 + tid;
  int node = gid >> 2, q = tid & 3, ln = tid >> 2;

  float4 t = make_float4(0.f, 0.f, 0.f, 0.f);
  if (node < n) {
    t = gather<4>(ptr, ep, hin, node, q);
    if (!LAST) hout[(size_t)node * 4 + q] = t;
  }
  tl4[ln * 5 + q] = t;
  __syncthreads();

  float4 a[4];
#pragma unroll
  for (int c = 0; c < 4; ++c) a[c] = make_float4(0.f, 0.f, 0.f, 0.f);
  if (!FIRST && node < n) {
#pragma unroll
    for (int c = 0; c < 4; ++c) a[c] = acc4[(size_t)node * 16 + 4 * q + c];
  }
#pragma unroll 4
  for (int i = 0; i < 16; ++i) {
    float tv = tl[ln * 20 + i];
#pragma unroll
    for (int c = 0; c < 4; ++c) {
      float4 wv = Wl[i * 16 + 4 * q + c];
      a[c].x = fmaf(tv, wv.x, a[c].x); a[c].y = fmaf(tv, wv.y, a[c].y);
      a[c].z = fmaf(tv, wv.z, a[c].z); a[c].w = fmaf(tv, wv.w, a[c].w);
    }
  }
  if (FIRST) {  // own-term x @ W0
    __syncthreads();
    float4 own = (node < n) ? hin[(size_t)node * 4 + q] : make_float4(0.f, 0.f, 0.f, 0.f);
    tl4[ln * 5 + q] = own;
    __syncthreads();
#pragma unroll 4
    for (int i = 0; i < 16; ++i) {
      float tv = tl[ln * 20 + i];
#pragma unroll
      for (int c = 0; c < 4; ++c) {
        float4 wv = W0l[i * 16 + 4 * q + c];
        a[c].x = fmaf(tv, wv.x, a[c].x); a[c].y = fmaf(tv, wv.y, a[c].y);
        a[c].z = fmaf(tv, wv.z, a[c].z); a[c].w = fmaf(tv, wv.w, a[c].w);
      }
    }
  }
  if (node >= n) return;

  if (LAST) {
#pragma unroll
    for (int c = 0; c < 4; ++c) {
      float4 b = bias4[4 * q + c];
      a[c].x += b.x; a[c].y += b.y; a[c].z += b.z; a[c].w += b.w;
      a[c].x = (a[c].x >= 0.f) ? a[c].x : 0.01f * a[c].x;
      a[c].y = (a[c].y >= 0.f) ? a[c].y : 0.01f * a[c].y;
      a[c].z = (a[c].z >= 0.f) ? a[c].z : 0.01f * a[c].z;
      a[c].w = (a[c].w >= 0.f) ? a[c].w : 0.01f * a[c].w;
      outbuf[(size_t)node * 16 + 4 * q + c] = a[c];  // activated, F=64 layout
    }
  } else {
#pragma unroll
    for (int c = 0; c < 4; ++c) acc4[(size_t)node * 16 + 4 * q + c] = a[c];
  }
}

extern "C" void kernel_launch(void* const* d_in, const int* in_sizes, int n_in,
                              void* d_out, int out_size, void* d_ws, size_t ws_size,
                              hipStream_t stream) {
  const float* x    = (const float*)d_in[0];
  const int*   ei   = (const int*)d_in[1];
  const float* ew   = (const float*)d_in[2];
  const float* W1   = (const float*)d_in[4];
  const float* b1   = (const float*)d_in[5];
  const float* W2   = (const float*)d_in[6];
  const float* b2   = (const float*)d_in[7];
  const float* Wout = (const float*)d_in[8];
  const float* bout = (const float*)d_in[9];
  float* out = (float*)d_out;

  const int N = in_sizes[0] / 16;
  const int E = in_sizes[2];
  const int* src = ei;
  const int* dst = ei + E;

  char* ws = (char*)d_ws;
  size_t off = 0;
  auto alloc = [&](size_t bytes) {
    char* p = ws + off;
    off = (off + bytes + 255) & ~(size_t)255;
    return p;
  };
  u64*   pack = (u64*)alloc((size_t)N * 8);
  float* dinv = (float*)alloc((size_t)N * 4);
  int*   ptr  = (int*)alloc(((size_t)N + 1) * 4);
  int*   bsum = (int*)alloc(4096);
  int*   rank = (int*)alloc((size_t)E * 4);
  int2*  ep   = (int2*)alloc((size_t)E * 8);
  float* B0   = (float*)alloc((size_t)N * 64 * 4);
  float* B1   = (float*)alloc((size_t)N * 64 * 4);
  float* B2   = (float*)alloc((size_t)N * 64 * 4);

  hipMemsetAsync(pack, 0, (size_t)N * 8, stream);

  int gE = (E + 255) / 256;
  int gN = (N + 255) / 256;
  degcount_k<<<gE, 256, 0, stream>>>(dst, ew, pack, rank, E);
  scan_blocks<<<gN, 256, 0, stream>>>(pack, dinv, ptr, bsum, N);
  scan_sums<<<1, 512, 0, stream>>>(bsum, gN);
  scan_add<<<gN, 256, 0, stream>>>(ptr, bsum, N, E);
  fill_k<<<gE, 256, 0, stream>>>(src, dst, ew, dinv, ptr, rank, ep, E);

  int g4  = (N * 4 + 255) / 256;   // layer-1 fused (4 lanes/node)
  int g16 = (N * 16 + 255) / 256;  // F=64 fused (16 lanes/node)

  const float4* x4 = (const float4*)x;
  float4* B04 = (float4*)B0; float4* B14 = (float4*)B1; float4* B24 = (float4*)B2;
  auto W1k = [&](int k) { return (const float4*)(W1 + (size_t)k * 1024); };
  auto W2k = [&](int l, int k) { return (const float4*)(W2 + ((size_t)l * 5 + k) * 4096); };

  // ---- Layer 1 (16 -> 64): acc in B2, t ping-pong B0/B1, output -> B1 ----
  ptag16_k<true,  false><<<g4, 256, 0, stream>>>(ptr, ep, x4,  B04, W1k(1), W1k(0), B24, nullptr, nullptr, N);
  ptag16_k<false, false><<<g4, 256, 0, stream>>>(ptr, ep, B04, B14, W1k(2), nullptr, B24, nullptr, nullptr, N);
  ptag16_k<false, false><<<g4, 256, 0, stream>>>(ptr, ep, B14, B04, W1k(3), nullptr, B24, nullptr, nullptr, N);
  ptag16_k<false, true ><<<g4, 256, 0, stream>>>(ptr, ep, B04, nullptr, W1k(4), nullptr, B24,
                                                 (const float4*)b1, B14, N);

  // ---- Layer 2 (64 -> 64): input B1, acc B2, output -> B1 ----
  ptag64_k<true,  false, false><<<g16, 256, 0, stream>>>(ptr, ep, B14, B04, W2k(0,1), W2k(0,0), B24,
                                                         nullptr, nullptr, nullptr, nullptr, N);
  ptag64_k<false, false, false><<<g16, 256, 0, stream>>>(ptr, ep, B04, B14, W2k(0,2), nullptr, B24,
                                                         nullptr, nullptr, nullptr, nullptr, N);
  ptag64_k<false, false, false><<<g16, 256, 0, stream>>>(ptr, ep, B14, B04, W2k(0,3), nullptr, B24,
                                                         nullptr, nullptr, nullptr, nullptr, N);
  ptag64_k<false, true,  false><<<g16, 256, 0, stream>>>(ptr, ep, B04, B14, W2k(0,4), nullptr, B24,
                                                         (const float4*)b2, nullptr, nullptr, nullptr, N);

  // ---- Layer 3 (64 -> 64) + head: input B1, acc B2, head -> out ----
  ptag64_k<true,  false, false><<<g16, 256, 0, stream>>>(ptr, ep, B14, B04, W2k(1,1), W2k(1,0), B24,
                                                         nullptr, nullptr, nullptr, nullptr, N);
  ptag64_k<false, false, false><<<g16, 256, 0, stream>>>(ptr, ep, B04, B14, W2k(1,2), nullptr, B24,
                                                         nullptr, nullptr, nullptr, nullptr, N);
  ptag64_k<false, false, false><<<g16, 256, 0, stream>>>(ptr, ep, B14, B04, W2k(1,3), nullptr, B24,
                                                         nullptr, nullptr, nullptr, nullptr, N);
  ptag64_k<false, true,  true ><<<g16, 256, 0, stream>>>(ptr, ep, B04, nullptr, W2k(1,4), nullptr, B24,
                                                         (const float4*)(b2 + 64), Wout, bout, out, N);
}

// Round 5
// 2065.681 us; speedup vs baseline: 1.4772x; 1.4772x over previous
//
#include <hip/hip_runtime.h>

// ---------------------------------------------------------------------------
// TAGCN node regression: 3 TAGConv layers (K=4) + linear head, fp32.
// CSR-by-dst built once per launch (rank from the degree atomic -> fill has
// no atomics). Propagation fused with matmul accumulation. F=64 fused kernel
// uses exactly 20480 B LDS (8 blocks/CU) via XOR-swizzled unpadded t-tile +
// two-phase W reuse in FIRST. R5: NO launch-bounds register clamp — R4's
// (256,8) halved the VGPR budget to 32 and spilled ~3 GB/dispatch to scratch.
// ---------------------------------------------------------------------------

typedef unsigned long long u64;

// one 64-bit atomic per edge: [count:16 | sum_w Q16.32 fixed point:48]
// old count = this edge's rank within its dst bucket -> CSR slot, no 2nd atomic
__global__ void degcount_k(const int* __restrict__ dst, const float* __restrict__ w,
                           u64* __restrict__ pack, int* __restrict__ rank, int E) {
  int e = blockIdx.x * blockDim.x + threadIdx.x;
  if (e >= E) return;
  int d = dst[e];
  u64 v = ((u64)1 << 48) | (u64)((double)w[e] * 4294967296.0);
  u64 old = atomicAdd(&pack[d], v);
  rank[e] = (int)(old >> 48);
}

// scan (256/block) fused with degree decode -> dinv
__global__ void scan_blocks(const u64* __restrict__ pack, float* __restrict__ dinv,
                            int* __restrict__ ptr, int* __restrict__ bsum, int n) {
  __shared__ int s[256];
  int tid = threadIdx.x;
  int i = blockIdx.x * 256 + tid;
  int v = 0;
  if (i < n) {
    u64 p = pack[i];
    v = (int)(p >> 48);
    float d = (float)((double)(p & 0xFFFFFFFFFFFFULL) * (1.0 / 4294967296.0));
    dinv[i] = (d > 0.f) ? rsqrtf(fmaxf(d, 1e-30f)) : 0.f;
  }
  s[tid] = v;
  __syncthreads();
#pragma unroll
  for (int off = 1; off < 256; off <<= 1) {
    int t = (tid >= off) ? s[tid - off] : 0;
    __syncthreads();
    s[tid] += t;
    __syncthreads();
  }
  if (i < n) ptr[i] = s[tid] - v;
  if (tid == 255) bsum[blockIdx.x] = s[255];
}

__global__ void scan_sums(int* __restrict__ bsum, int nb) {
  __shared__ int s[512];
  int tid = threadIdx.x;
  int v = (tid < nb) ? bsum[tid] : 0;
  s[tid] = v;
  __syncthreads();
#pragma unroll
  for (int off = 1; off < 512; off <<= 1) {
    int t = (tid >= off) ? s[tid - off] : 0;
    __syncthreads();
    s[tid] += t;
    __syncthreads();
  }
  if (tid < nb) bsum[tid] = s[tid] - v;
}

__global__ void scan_add(int* __restrict__ ptr, const int* __restrict__ bsum, int n, int E) {
  int i = blockIdx.x * blockDim.x + threadIdx.x;
  if (i < n) ptr[i] += bsum[i >> 8];
  if (i == 0) ptr[n] = E;
}

// scatter edges into CSR slots (atomic-free); payload = {src, folded norm}
__global__ void fill_k(const int* __restrict__ src, const int* __restrict__ dst,
                       const float* __restrict__ w, const float* __restrict__ dinv,
                       const int* __restrict__ ptr, const int* __restrict__ rank,
                       int2* __restrict__ ep, int E) {
  int e = blockIdx.x * blockDim.x + threadIdx.x;
  if (e >= E) return;
  int s = src[e], d = dst[e];
  float nv = dinv[s] * w[e] * dinv[d];
  int pos = ptr[d] + rank[e];
  ep[pos] = make_int2(s, __float_as_int(nv));
}

// gather t[f4] = sum_e w_e * hin[src_e][f4]
template <int F4>
__device__ __forceinline__ float4 gather(const int* __restrict__ ptr, const int2* __restrict__ ep,
                                         const float4* __restrict__ hin, int node, int f4) {
  int e0 = ptr[node], e1 = ptr[node + 1];
  float4 a = make_float4(0.f, 0.f, 0.f, 0.f);
  int e = e0;
  if ((e & 1) && e < e1) {
    int2 p = ep[e];
    float w0 = __int_as_float(p.y);
    float4 h = hin[(size_t)p.x * F4 + f4];
    a.x += w0 * h.x; a.y += w0 * h.y; a.z += w0 * h.z; a.w += w0 * h.w;
    ++e;
  }
  for (; e + 1 < e1; e += 2) {
    int4 p = *(const int4*)(ep + e);  // 2 edges, 16B aligned
    float w0 = __int_as_float(p.y), w1 = __int_as_float(p.w);
    float4 h0 = hin[(size_t)p.x * F4 + f4];
    float4 h1 = hin[(size_t)p.z * F4 + f4];
    a.x += w0 * h0.x; a.y += w0 * h0.y; a.z += w0 * h0.z; a.w += w0 * h0.w;
    a.x += w1 * h1.x; a.y += w1 * h1.y; a.z += w1 * h1.z; a.w += w1 * h1.w;
  }
  if (e < e1) {
    int2 p = ep[e];
    float w0 = __int_as_float(p.y);
    float4 h = hin[(size_t)p.x * F4 + f4];
    a.x += w0 * h.x; a.y += w0 * h.y; a.z += w0 * h.z; a.w += w0 * h.w;
  }
  return a;
}

// ---------- fused prop + matmul, F=64 (16 lanes/node, 16 nodes/block) ----------
// LDS = 16K W + 4K XOR-swizzled t tile = 20480 B exactly -> 8 blocks/CU when
// VGPR <= 64 (natural allocation ~52). NO register clamp (see R4 post-mortem).
template <bool FIRST, bool LAST, bool HEAD>
__launch_bounds__(256)
__global__ void ptag64_k(const int* __restrict__ ptr, const int2* __restrict__ ep,
                         const float4* __restrict__ hin, float4* __restrict__ hout,
                         const float4* __restrict__ Wk4, const float4* __restrict__ W04,
                         float4* __restrict__ acc4, const float4* __restrict__ bias4,
                         const float* __restrict__ Wout, const float* __restrict__ bout,
                         float* __restrict__ outv, int n) {
  __shared__ float4 Wl[1024];  // 64x64 weight (reused for W0 in FIRST phase B)
  __shared__ float4 tl4[256];  // t tile, slot = ln*16 + (j4^ln)  (bank-clean)
  int tid = threadIdx.x;
  for (int i = tid; i < 1024; i += 256) Wl[i] = Wk4[i];
  int gid = blockIdx.x * 256 + tid;
  int node = gid >> 4, j4 = gid & 15, ln = tid >> 4;

  float4 t = make_float4(0.f, 0.f, 0.f, 0.f);
  if (node < n) {
    t = gather<16>(ptr, ep, hin, node, j4);
    if (!LAST) hout[(size_t)node * 16 + j4] = t;
  }
  tl4[ln * 16 + (j4 ^ ln)] = t;
  __syncthreads();

  float4 a = make_float4(0.f, 0.f, 0.f, 0.f);
  if (!FIRST && node < n) a = acc4[(size_t)node * 16 + j4];
#pragma unroll
  for (int q = 0; q < 16; ++q) {
    float4 tv = tl4[ln * 16 + (q ^ ln)];  // = t of lane q in this node group
    float4 w0 = Wl[(4 * q + 0) * 16 + j4];
    float4 w1 = Wl[(4 * q + 1) * 16 + j4];
    float4 w2 = Wl[(4 * q + 2) * 16 + j4];
    float4 w3 = Wl[(4 * q + 3) * 16 + j4];
    a.x = fmaf(tv.x, w0.x, a.x); a.y = fmaf(tv.x, w0.y, a.y);
    a.z = fmaf(tv.x, w0.z, a.z); a.w = fmaf(tv.x, w0.w, a.w);
    a.x = fmaf(tv.y, w1.x, a.x); a.y = fmaf(tv.y, w1.y, a.y);
    a.z = fmaf(tv.y, w1.z, a.z); a.w = fmaf(tv.y, w1.w, a.w);
    a.x = fmaf(tv.z, w2.x, a.x); a.y = fmaf(tv.z, w2.y, a.y);
    a.z = fmaf(tv.z, w2.z, a.z); a.w = fmaf(tv.z, w2.w, a.w);
    a.x = fmaf(tv.w, w3.x, a.x); a.y = fmaf(tv.w, w3.y, a.y);
    a.z = fmaf(tv.w, w3.z, a.z); a.w = fmaf(tv.w, w3.w, a.w);
  }
  if (FIRST) {  // phase B: own-term h0 @ W0, same LDS buffers
    __syncthreads();  // everyone done reading Wl/tl4
    for (int i = tid; i < 1024; i += 256) Wl[i] = W04[i];
    float4 own = (node < n) ? hin[(size_t)node * 16 + j4] : make_float4(0.f, 0.f, 0.f, 0.f);
    tl4[ln * 16 + (j4 ^ ln)] = own;
    __syncthreads();
#pragma unroll
    for (int q = 0; q < 16; ++q) {
      float4 tv = tl4[ln * 16 + (q ^ ln)];
      float4 w0 = Wl[(4 * q + 0) * 16 + j4];
      float4 w1 = Wl[(4 * q + 1) * 16 + j4];
      float4 w2 = Wl[(4 * q + 2) * 16 + j4];
      float4 w3 = Wl[(4 * q + 3) * 16 + j4];
      a.x = fmaf(tv.x, w0.x, a.x); a.y = fmaf(tv.x, w0.y, a.y);
      a.z = fmaf(tv.x, w0.z, a.z); a.w = fmaf(tv.x, w0.w, a.w);
      a.x = fmaf(tv.y, w1.x, a.x); a.y = fmaf(tv.y, w1.y, a.y);
      a.z = fmaf(tv.y, w1.z, a.z); a.w = fmaf(tv.y, w1.w, a.w);
      a.x = fmaf(tv.z, w2.x, a.x); a.y = fmaf(tv.z, w2.y, a.y);
      a.z = fmaf(tv.z, w2.z, a.z); a.w = fmaf(tv.z, w2.w, a.w);
      a.x = fmaf(tv.w, w3.x, a.x); a.y = fmaf(tv.w, w3.y, a.y);
      a.z = fmaf(tv.w, w3.z, a.z); a.w = fmaf(tv.w, w3.w, a.w);
    }
  }
  if (node >= n) return;  // no barriers below

  if (LAST) {
    float4 b = bias4[j4];
    a.x += b.x; a.y += b.y; a.z += b.z; a.w += b.w;
    a.x = (a.x >= 0.f) ? a.x : 0.01f * a.x;
    a.y = (a.y >= 0.f) ? a.y : 0.01f * a.y;
    a.z = (a.z >= 0.f) ? a.z : 0.01f * a.z;
    a.w = (a.w >= 0.f) ? a.w : 0.01f * a.w;
    if (HEAD) {
      float v = a.x * Wout[4 * j4] + a.y * Wout[4 * j4 + 1] +
                a.z * Wout[4 * j4 + 2] + a.w * Wout[4 * j4 + 3];
      v += __shfl_down(v, 8, 16);
      v += __shfl_down(v, 4, 16);
      v += __shfl_down(v, 2, 16);
      v += __shfl_down(v, 1, 16);
      if (j4 == 0) outv[node] = v + bout[0];
    } else {
      hout[(size_t)node * 16 + j4] = a;  // activated layer output
    }
  } else {
    acc4[(size_t)node * 16 + j4] = a;
  }
}

// ---------- fused prop + matmul, layer 1: F_in=16 (4 lanes/node, 64 nodes/block) ----------
template <bool FIRST, bool LAST>
__launch_bounds__(256)
__global__ void ptag16_k(const int* __restrict__ ptr, const int2* __restrict__ ep,
                         const float4* __restrict__ hin, float4* __restrict__ hout,
                         const float4* __restrict__ Wk4, const float4* __restrict__ W04,
                         float4* __restrict__ acc4, const float4* __restrict__ bias4,
                         float4* __restrict__ outbuf, int n) {
  __shared__ float4 Wl[256];               // 16x64 W_k
  __shared__ float4 W0l[FIRST ? 256 : 1];  // 16x64 W_0
  __shared__ float4 tl4[64 * 5];           // t tile, stride 5 float4
  const float* tl = (const float*)tl4;
  int tid = threadIdx.x;
  Wl[tid] = Wk4[tid];
  if (FIRST) W0l[tid] = W04[tid];
  int gid = blockIdx.x * 256 + tid;
  int node = gid >> 2, q = tid & 3, ln = tid >> 2;

  float4 t = make_float4(0.f, 0.f, 0.f, 0.f);
  if (node < n) {
    t = gather<4>(ptr, ep, hin, node, q);
    if (!LAST) hout[(size_t)node * 4 + q] = t;
  }
  tl4[ln * 5 + q] = t;
  __syncthreads();

  float4 a[4];
#pragma unroll
  for (int c = 0; c < 4; ++c) a[c] = make_float4(0.f, 0.f, 0.f, 0.f);
  if (!FIRST && node < n) {
#pragma unroll
    for (int c = 0; c < 4; ++c) a[c] = acc4[(size_t)node * 16 + 4 * q + c];
  }
#pragma unroll 4
  for (int i = 0; i < 16; ++i) {
    float tv = tl[ln * 20 + i];
#pragma unroll
    for (int c = 0; c < 4; ++c) {
      float4 wv = Wl[i * 16 + 4 * q + c];
      a[c].x = fmaf(tv, wv.x, a[c].x); a[c].y = fmaf(tv, wv.y, a[c].y);
      a[c].z = fmaf(tv, wv.z, a[c].z); a[c].w = fmaf(tv, wv.w, a[c].w);
    }
  }
  if (FIRST) {  // own-term x @ W0
    __syncthreads();
    float4 own = (node < n) ? hin[(size_t)node * 4 + q] : make_float4(0.f, 0.f, 0.f, 0.f);
    tl4[ln * 5 + q] = own;
    __syncthreads();
#pragma unroll 4
    for (int i = 0; i < 16; ++i) {
      float tv = tl[ln * 20 + i];
#pragma unroll
      for (int c = 0; c < 4; ++c) {
        float4 wv = W0l[i * 16 + 4 * q + c];
        a[c].x = fmaf(tv, wv.x, a[c].x); a[c].y = fmaf(tv, wv.y, a[c].y);
        a[c].z = fmaf(tv, wv.z, a[c].z); a[c].w = fmaf(tv, wv.w, a[c].w);
      }
    }
  }
  if (node >= n) return;

  if (LAST) {
#pragma unroll
    for (int c = 0; c < 4; ++c) {
      float4 b = bias4[4 * q + c];
      a[c].x += b.x; a[c].y += b.y; a[c].z += b.z; a[c].w += b.w;
      a[c].x = (a[c].x >= 0.f) ? a[c].x : 0.01f * a[c].x;
      a[c].y = (a[c].y >= 0.f) ? a[c].y : 0.01f * a[c].y;
      a[c].z = (a[c].z >= 0.f) ? a[c].z : 0.01f * a[c].z;
      a[c].w = (a[c].w >= 0.f) ? a[c].w : 0.01f * a[c].w;
      outbuf[(size_t)node * 16 + 4 * q + c] = a[c];  // activated, F=64 layout
    }
  } else {
#pragma unroll
    for (int c = 0; c < 4; ++c) acc4[(size_t)node * 16 + 4 * q + c] = a[c];
  }
}

extern "C" void kernel_launch(void* const* d_in, const int* in_sizes, int n_in,
                              void* d_out, int out_size, void* d_ws, size_t ws_size,
                              hipStream_t stream) {
  const float* x    = (const float*)d_in[0];
  const int*   ei   = (const int*)d_in[1];
  const float* ew   = (const float*)d_in[2];
  const float* W1   = (const float*)d_in[4];
  const float* b1   = (const float*)d_in[5];
  const float* W2   = (const float*)d_in[6];
  const float* b2   = (const float*)d_in[7];
  const float* Wout = (const float*)d_in[8];
  const float* bout = (const float*)d_in[9];
  float* out = (float*)d_out;

  const int N = in_sizes[0] / 16;
  const int E = in_sizes[2];
  const int* src = ei;
  const int* dst = ei + E;

  char* ws = (char*)d_ws;
  size_t off = 0;
  auto alloc = [&](size_t bytes) {
    char* p = ws + off;
    off = (off + bytes + 255) & ~(size_t)255;
    return p;
  };
  u64*   pack = (u64*)alloc((size_t)N * 8);
  float* dinv = (float*)alloc((size_t)N * 4);
  int*   ptr  = (int*)alloc(((size_t)N + 1) * 4);
  int*   bsum = (int*)alloc(4096);
  int*   rank = (int*)alloc((size_t)E * 4);
  int2*  ep   = (int2*)alloc((size_t)E * 8);
  float* B0   = (float*)alloc((size_t)N * 64 * 4);
  float* B1   = (float*)alloc((size_t)N * 64 * 4);
  float* B2   = (float*)alloc((size_t)N * 64 * 4);

  hipMemsetAsync(pack, 0, (size_t)N * 8, stream);

  int gE = (E + 255) / 256;
  int gN = (N + 255) / 256;
  degcount_k<<<gE, 256, 0, stream>>>(dst, ew, pack, rank, E);
  scan_blocks<<<gN, 256, 0, stream>>>(pack, dinv, ptr, bsum, N);
  scan_sums<<<1, 512, 0, stream>>>(bsum, gN);
  scan_add<<<gN, 256, 0, stream>>>(ptr, bsum, N, E);
  fill_k<<<gE, 256, 0, stream>>>(src, dst, ew, dinv, ptr, rank, ep, E);

  int g4  = (N * 4 + 255) / 256;   // layer-1 fused (4 lanes/node)
  int g16 = (N * 16 + 255) / 256;  // F=64 fused (16 lanes/node)

  const float4* x4 = (const float4*)x;
  float4* B04 = (float4*)B0; float4* B14 = (float4*)B1; float4* B24 = (float4*)B2;
  auto W1k = [&](int k) { return (const float4*)(W1 + (size_t)k * 1024); };
  auto W2k = [&](int l, int k) { return (const float4*)(W2 + ((size_t)l * 5 + k) * 4096); };

  // ---- Layer 1 (16 -> 64): acc in B2, t ping-pong B0/B1, output -> B1 ----
  ptag16_k<true,  false><<<g4, 256, 0, stream>>>(ptr, ep, x4,  B04, W1k(1), W1k(0), B24, nullptr, nullptr, N);
  ptag16_k<false, false><<<g4, 256, 0, stream>>>(ptr, ep, B04, B14, W1k(2), nullptr, B24, nullptr, nullptr, N);
  ptag16_k<false, false><<<g4, 256, 0, stream>>>(ptr, ep, B14, B04, W1k(3), nullptr, B24, nullptr, nullptr, N);
  ptag16_k<false, true ><<<g4, 256, 0, stream>>>(ptr, ep, B04, nullptr, W1k(4), nullptr, B24,
                                                 (const float4*)b1, B14, N);

  // ---- Layer 2 (64 -> 64): input B1, acc B2, output -> B1 ----
  ptag64_k<true,  false, false><<<g16, 256, 0, stream>>>(ptr, ep, B14, B04, W2k(0,1), W2k(0,0), B24,
                                                         nullptr, nullptr, nullptr, nullptr, N);
  ptag64_k<false, false, false><<<g16, 256, 0, stream>>>(ptr, ep, B04, B14, W2k(0,2), nullptr, B24,
                                                         nullptr, nullptr, nullptr, nullptr, N);
  ptag64_k<false, false, false><<<g16, 256, 0, stream>>>(ptr, ep, B14, B04, W2k(0,3), nullptr, B24,
                                                         nullptr, nullptr, nullptr, nullptr, N);
  ptag64_k<false, true,  false><<<g16, 256, 0, stream>>>(ptr, ep, B04, B14, W2k(0,4), nullptr, B24,
                                                         (const float4*)b2, nullptr, nullptr, nullptr, N);

  // ---- Layer 3 (64 -> 64) + head: input B1, acc B2, head -> out ----
  ptag64_k<true,  false, false><<<g16, 256, 0, stream>>>(ptr, ep, B14, B04, W2k(1,1), W2k(1,0), B24,
                                                         nullptr, nullptr, nullptr, nullptr, N);
  ptag64_k<false, false, false><<<g16, 256, 0, stream>>>(ptr, ep, B04, B14, W2k(1,2), nullptr, B24,
                                                         nullptr, nullptr, nullptr, nullptr, N);
  ptag64_k<false, false, false><<<g16, 256, 0, stream>>>(ptr, ep, B14, B04, W2k(1,3), nullptr, B24,
                                                         nullptr, nullptr, nullptr, nullptr, N);
  ptag64_k<false, true,  true ><<<g16, 256, 0, stream>>>(ptr, ep, B04, nullptr, W2k(1,4), nullptr, B24,
                                                         (const float4*)(b2 + 64), Wout, bout, out, N);
}

// Round 6
// 1639.706 us; speedup vs baseline: 1.8610x; 1.2598x over previous
//
#include <hip/hip_runtime.h>

// ---------------------------------------------------------------------------
// TAGCN node regression: 3 TAGConv layers (K=4) + linear head, fp32.
// CSR-by-dst built once per launch (rank from the degree atomic -> fill has
// no atomics). Propagation fused with matmul accumulation. F=64 fused kernel:
// exactly 20480 B LDS (8 blocks/CU) via XOR-swizzled t-tile + two-phase W
// reuse in FIRST. R6: mm inner loop restored to R3's scalar-t-broadcast form
// (52 VGPR) — R5's float4-tv/4xW unrolled loop ballooned to 176 VGPR (11% occ).
// No launch-bounds min-waves clamp (R4: clamp -> 3 GB scratch spill).
// ---------------------------------------------------------------------------

typedef unsigned long long u64;

// one 64-bit atomic per edge: [count:16 | sum_w Q16.32 fixed point:48]
// old count = this edge's rank within its dst bucket -> CSR slot, no 2nd atomic
__global__ void degcount_k(const int* __restrict__ dst, const float* __restrict__ w,
                           u64* __restrict__ pack, int* __restrict__ rank, int E) {
  int e = blockIdx.x * blockDim.x + threadIdx.x;
  if (e >= E) return;
  int d = dst[e];
  u64 v = ((u64)1 << 48) | (u64)((double)w[e] * 4294967296.0);
  u64 old = atomicAdd(&pack[d], v);
  rank[e] = (int)(old >> 48);
}

// scan (256/block) fused with degree decode -> dinv
__global__ void scan_blocks(const u64* __restrict__ pack, float* __restrict__ dinv,
                            int* __restrict__ ptr, int* __restrict__ bsum, int n) {
  __shared__ int s[256];
  int tid = threadIdx.x;
  int i = blockIdx.x * 256 + tid;
  int v = 0;
  if (i < n) {
    u64 p = pack[i];
    v = (int)(p >> 48);
    float d = (float)((double)(p & 0xFFFFFFFFFFFFULL) * (1.0 / 4294967296.0));
    dinv[i] = (d > 0.f) ? rsqrtf(fmaxf(d, 1e-30f)) : 0.f;
  }
  s[tid] = v;
  __syncthreads();
#pragma unroll
  for (int off = 1; off < 256; off <<= 1) {
    int t = (tid >= off) ? s[tid - off] : 0;
    __syncthreads();
    s[tid] += t;
    __syncthreads();
  }
  if (i < n) ptr[i] = s[tid] - v;
  if (tid == 255) bsum[blockIdx.x] = s[255];
}

__global__ void scan_sums(int* __restrict__ bsum, int nb) {
  __shared__ int s[512];
  int tid = threadIdx.x;
  int v = (tid < nb) ? bsum[tid] : 0;
  s[tid] = v;
  __syncthreads();
#pragma unroll
  for (int off = 1; off < 512; off <<= 1) {
    int t = (tid >= off) ? s[tid - off] : 0;
    __syncthreads();
    s[tid] += t;
    __syncthreads();
  }
  if (tid < nb) bsum[tid] = s[tid] - v;
}

__global__ void scan_add(int* __restrict__ ptr, const int* __restrict__ bsum, int n, int E) {
  int i = blockIdx.x * blockDim.x + threadIdx.x;
  if (i < n) ptr[i] += bsum[i >> 8];
  if (i == 0) ptr[n] = E;
}

// scatter edges into CSR slots (atomic-free); payload = {src, folded norm}
__global__ void fill_k(const int* __restrict__ src, const int* __restrict__ dst,
                       const float* __restrict__ w, const float* __restrict__ dinv,
                       const int* __restrict__ ptr, const int* __restrict__ rank,
                       int2* __restrict__ ep, int E) {
  int e = blockIdx.x * blockDim.x + threadIdx.x;
  if (e >= E) return;
  int s = src[e], d = dst[e];
  float nv = dinv[s] * w[e] * dinv[d];
  int pos = ptr[d] + rank[e];
  ep[pos] = make_int2(s, __float_as_int(nv));
}

// gather t[f4] = sum_e w_e * hin[src_e][f4]
template <int F4>
__device__ __forceinline__ float4 gather(const int* __restrict__ ptr, const int2* __restrict__ ep,
                                         const float4* __restrict__ hin, int node, int f4) {
  int e0 = ptr[node], e1 = ptr[node + 1];
  float4 a = make_float4(0.f, 0.f, 0.f, 0.f);
  int e = e0;
  if ((e & 1) && e < e1) {
    int2 p = ep[e];
    float w0 = __int_as_float(p.y);
    float4 h = hin[(size_t)p.x * F4 + f4];
    a.x += w0 * h.x; a.y += w0 * h.y; a.z += w0 * h.z; a.w += w0 * h.w;
    ++e;
  }
  for (; e + 1 < e1; e += 2) {
    int4 p = *(const int4*)(ep + e);  // 2 edges, 16B aligned
    float w0 = __int_as_float(p.y), w1 = __int_as_float(p.w);
    float4 h0 = hin[(size_t)p.x * F4 + f4];
    float4 h1 = hin[(size_t)p.z * F4 + f4];
    a.x += w0 * h0.x; a.y += w0 * h0.y; a.z += w0 * h0.z; a.w += w0 * h0.w;
    a.x += w1 * h1.x; a.y += w1 * h1.y; a.z += w1 * h1.z; a.w += w1 * h1.w;
  }
  if (e < e1) {
    int2 p = ep[e];
    float w0 = __int_as_float(p.y);
    float4 h = hin[(size_t)p.x * F4 + f4];
    a.x += w0 * h.x; a.y += w0 * h.y; a.z += w0 * h.z; a.w += w0 * h.w;
  }
  return a;
}

// scalar-broadcast mm accumulate: a += t(group ln) @ W, R3's 52-VGPR shape.
// t element i of group ln lives at word ln*64 + (((i>>2)^ln)<<2 | (i&3)).
__device__ __forceinline__ void mm_acc(const float* __restrict__ tl, const float4* __restrict__ Wl,
                                       int ln, int j4, float4& a) {
#pragma unroll 8
  for (int i = 0; i < 64; ++i) {
    float tv = tl[ln * 64 + ((((i >> 2) ^ ln) << 2) | (i & 3))];
    float4 wv = Wl[i * 16 + j4];
    a.x = fmaf(tv, wv.x, a.x); a.y = fmaf(tv, wv.y, a.y);
    a.z = fmaf(tv, wv.z, a.z); a.w = fmaf(tv, wv.w, a.w);
  }
}

// ---------- fused prop + matmul, F=64 (16 lanes/node, 16 nodes/block) ----------
// LDS = 16K W + 4K XOR-swizzled t tile = 20480 B exactly -> 8 blocks/CU when
// VGPR <= 64 (R3 evidence: this loop shape compiles to ~52).
template <bool FIRST, bool LAST, bool HEAD>
__launch_bounds__(256)
__global__ void ptag64_k(const int* __restrict__ ptr, const int2* __restrict__ ep,
                         const float4* __restrict__ hin, float4* __restrict__ hout,
                         const float4* __restrict__ Wk4, const float4* __restrict__ W04,
                         float4* __restrict__ acc4, const float4* __restrict__ bias4,
                         const float* __restrict__ Wout, const float* __restrict__ bout,
                         float* __restrict__ outv, int n) {
  __shared__ float4 Wl[1024];  // 64x64 weight (reused for W0 in FIRST phase B)
  __shared__ float4 tl4[256];  // t tile, slot = ln*16 + (j4^ln)  (bank-clean)
  const float* tl = (const float*)tl4;
  int tid = threadIdx.x;
  for (int i = tid; i < 1024; i += 256) Wl[i] = Wk4[i];
  int gid = blockIdx.x * 256 + tid;
  int node = gid >> 4, j4 = gid & 15, ln = tid >> 4;

  float4 t = make_float4(0.f, 0.f, 0.f, 0.f);
  if (node < n) {
    t = gather<16>(ptr, ep, hin, node, j4);
    if (!LAST) hout[(size_t)node * 16 + j4] = t;
  }
  tl4[ln * 16 + (j4 ^ ln)] = t;
  __syncthreads();

  float4 a = make_float4(0.f, 0.f, 0.f, 0.f);
  if (!FIRST && node < n) a = acc4[(size_t)node * 16 + j4];
  mm_acc(tl, Wl, ln, j4, a);
  if (FIRST) {  // phase B: own-term h0 @ W0, same LDS buffers
    __syncthreads();  // everyone done reading Wl/tl4
    for (int i = tid; i < 1024; i += 256) Wl[i] = W04[i];
    float4 own = (node < n) ? hin[(size_t)node * 16 + j4] : make_float4(0.f, 0.f, 0.f, 0.f);
    tl4[ln * 16 + (j4 ^ ln)] = own;
    __syncthreads();
    mm_acc(tl, Wl, ln, j4, a);
  }
  if (node >= n) return;  // no barriers below

  if (LAST) {
    float4 b = bias4[j4];
    a.x += b.x; a.y += b.y; a.z += b.z; a.w += b.w;
    a.x = (a.x >= 0.f) ? a.x : 0.01f * a.x;
    a.y = (a.y >= 0.f) ? a.y : 0.01f * a.y;
    a.z = (a.z >= 0.f) ? a.z : 0.01f * a.z;
    a.w = (a.w >= 0.f) ? a.w : 0.01f * a.w;
    if (HEAD) {
      float v = a.x * Wout[4 * j4] + a.y * Wout[4 * j4 + 1] +
                a.z * Wout[4 * j4 + 2] + a.w * Wout[4 * j4 + 3];
      v += __shfl_down(v, 8, 16);
      v += __shfl_down(v, 4, 16);
      v += __shfl_down(v, 2, 16);
      v += __shfl_down(v, 1, 16);
      if (j4 == 0) outv[node] = v + bout[0];
    } else {
      hout[(size_t)node * 16 + j4] = a;  // activated layer output
    }
  } else {
    acc4[(size_t)node * 16 + j4] = a;
  }
}

// ---------- fused prop + matmul, layer 1: F_in=16 (4 lanes/node, 64 nodes/block) ----------
template <bool FIRST, bool LAST>
__launch_bounds__(256)
__global__ void ptag16_k(const int* __restrict__ ptr, const int2* __restrict__ ep,
                         const float4* __restrict__ hin, float4* __restrict__ hout,
                         const float4* __restrict__ Wk4, const float4* __restrict__ W04,
                         float4* __restrict__ acc4, const float4* __restrict__ bias4,
                         float4* __restrict__ outbuf, int n) {
  __shared__ float4 Wl[256];               // 16x64 W_k
  __shared__ float4 W0l[FIRST ? 256 : 1];  // 16x64 W_0
  __shared__ float4 tl4[64 * 5];           // t tile, stride 5 float4
  const float* tl = (const float*)tl4;
  int tid = threadIdx.x;
  Wl[tid] = Wk4[tid];
  if (FIRST) W0l[tid] = W04[tid];
  int gid = blockIdx.x * 256 + tid;
  int node = gid >> 2, q = tid & 3, ln = tid >> 2;

  float4 t = make_float4(0.f, 0.f, 0.f, 0.f);
  if (node < n) {
    t = gather<4>(ptr, ep, hin, node, q);
    if (!LAST) hout[(size_t)node * 4 + q] = t;
  }
  tl4[ln * 5 + q] = t;
  __syncthreads();

  float4 a[4];
#pragma unroll
  for (int c = 0; c < 4; ++c) a[c] = make_float4(0.f, 0.f, 0.f, 0.f);
  if (!FIRST && node < n) {
#pragma unroll
    for (int c = 0; c < 4; ++c) a[c] = acc4[(size_t)node * 16 + 4 * q + c];
  }
#pragma unroll 4
  for (int i = 0; i < 16; ++i) {
    float tv = tl[ln * 20 + i];
#pragma unroll
    for (int c = 0; c < 4; ++c) {
      float4 wv = Wl[i * 16 + 4 * q + c];
      a[c].x = fmaf(tv, wv.x, a[c].x); a[c].y = fmaf(tv, wv.y, a[c].y);
      a[c].z = fmaf(tv, wv.z, a[c].z); a[c].w = fmaf(tv, wv.w, a[c].w);
    }
  }
  if (FIRST) {  // own-term x @ W0
    __syncthreads();
    float4 own = (node < n) ? hin[(size_t)node * 4 + q] : make_float4(0.f, 0.f, 0.f, 0.f);
    tl4[ln * 5 + q] = own;
    __syncthreads();
#pragma unroll 4
    for (int i = 0; i < 16; ++i) {
      float tv = tl[ln * 20 + i];
#pragma unroll
      for (int c = 0; c < 4; ++c) {
        float4 wv = W0l[i * 16 + 4 * q + c];
        a[c].x = fmaf(tv, wv.x, a[c].x); a[c].y = fmaf(tv, wv.y, a[c].y);
        a[c].z = fmaf(tv, wv.z, a[c].z); a[c].w = fmaf(tv, wv.w, a[c].w);
      }
    }
  }
  if (node >= n) return;

  if (LAST) {
#pragma unroll
    for (int c = 0; c < 4; ++c) {
      float4 b = bias4[4 * q + c];
      a[c].x += b.x; a[c].y += b.y; a[c].z += b.z; a[c].w += b.w;
      a[c].x = (a[c].x >= 0.f) ? a[c].x : 0.01f * a[c].x;
      a[c].y = (a[c].y >= 0.f) ? a[c].y : 0.01f * a[c].y;
      a[c].z = (a[c].z >= 0.f) ? a[c].z : 0.01f * a[c].z;
      a[c].w = (a[c].w >= 0.f) ? a[c].w : 0.01f * a[c].w;
      outbuf[(size_t)node * 16 + 4 * q + c] = a[c];  // activated, F=64 layout
    }
  } else {
#pragma unroll
    for (int c = 0; c < 4; ++c) acc4[(size_t)node * 16 + 4 * q + c] = a[c];
  }
}

extern "C" void kernel_launch(void* const* d_in, const int* in_sizes, int n_in,
                              void* d_out, int out_size, void* d_ws, size_t ws_size,
                              hipStream_t stream) {
  const float* x    = (const float*)d_in[0];
  const int*   ei   = (const int*)d_in[1];
  const float* ew   = (const float*)d_in[2];
  const float* W1   = (const float*)d_in[4];
  const float* b1   = (const float*)d_in[5];
  const float* W2   = (const float*)d_in[6];
  const float* b2   = (const float*)d_in[7];
  const float* Wout = (const float*)d_in[8];
  const float* bout = (const float*)d_in[9];
  float* out = (float*)d_out;

  const int N = in_sizes[0] / 16;
  const int E = in_sizes[2];
  const int* src = ei;
  const int* dst = ei + E;

  char* ws = (char*)d_ws;
  size_t off = 0;
  auto alloc = [&](size_t bytes) {
    char* p = ws + off;
    off = (off + bytes + 255) & ~(size_t)255;
    return p;
  };
  u64*   pack = (u64*)alloc((size_t)N * 8);
  float* dinv = (float*)alloc((size_t)N * 4);
  int*   ptr  = (int*)alloc(((size_t)N + 1) * 4);
  int*   bsum = (int*)alloc(4096);
  int*   rank = (int*)alloc((size_t)E * 4);
  int2*  ep   = (int2*)alloc((size_t)E * 8);
  float* B0   = (float*)alloc((size_t)N * 64 * 4);
  float* B1   = (float*)alloc((size_t)N * 64 * 4);
  float* B2   = (float*)alloc((size_t)N * 64 * 4);

  hipMemsetAsync(pack, 0, (size_t)N * 8, stream);

  int gE = (E + 255) / 256;
  int gN = (N + 255) / 256;
  degcount_k<<<gE, 256, 0, stream>>>(dst, ew, pack, rank, E);
  scan_blocks<<<gN, 256, 0, stream>>>(pack, dinv, ptr, bsum, N);
  scan_sums<<<1, 512, 0, stream>>>(bsum, gN);
  scan_add<<<gN, 256, 0, stream>>>(ptr, bsum, N, E);
  fill_k<<<gE, 256, 0, stream>>>(src, dst, ew, dinv, ptr, rank, ep, E);

  int g4  = (N * 4 + 255) / 256;   // layer-1 fused (4 lanes/node)
  int g16 = (N * 16 + 255) / 256;  // F=64 fused (16 lanes/node)

  const float4* x4 = (const float4*)x;
  float4* B04 = (float4*)B0; float4* B14 = (float4*)B1; float4* B24 = (float4*)B2;
  auto W1k = [&](int k) { return (const float4*)(W1 + (size_t)k * 1024); };
  auto W2k = [&](int l, int k) { return (const float4*)(W2 + ((size_t)l * 5 + k) * 4096); };

  // ---- Layer 1 (16 -> 64): acc in B2, t ping-pong B0/B1, output -> B1 ----
  ptag16_k<true,  false><<<g4, 256, 0, stream>>>(ptr, ep, x4,  B04, W1k(1), W1k(0), B24, nullptr, nullptr, N);
  ptag16_k<false, false><<<g4, 256, 0, stream>>>(ptr, ep, B04, B14, W1k(2), nullptr, B24, nullptr, nullptr, N);
  ptag16_k<false, false><<<g4, 256, 0, stream>>>(ptr, ep, B14, B04, W1k(3), nullptr, B24, nullptr, nullptr, N);
  ptag16_k<false, true ><<<g4, 256, 0, stream>>>(ptr, ep, B04, nullptr, W1k(4), nullptr, B24,
                                                 (const float4*)b1, B14, N);

  // ---- Layer 2 (64 -> 64): input B1, acc B2, output -> B1 ----
  ptag64_k<true,  false, false><<<g16, 256, 0, stream>>>(ptr, ep, B14, B04, W2k(0,1), W2k(0,0), B24,
                                                         nullptr, nullptr, nullptr, nullptr, N);
  ptag64_k<false, false, false><<<g16, 256, 0, stream>>>(ptr, ep, B04, B14, W2k(0,2), nullptr, B24,
                                                         nullptr, nullptr, nullptr, nullptr, N);
  ptag64_k<false, false, false><<<g16, 256, 0, stream>>>(ptr, ep, B14, B04, W2k(0,3), nullptr, B24,
                                                         nullptr, nullptr, nullptr, nullptr, N);
  ptag64_k<false, true,  false><<<g16, 256, 0, stream>>>(ptr, ep, B04, B14, W2k(0,4), nullptr, B24,
                                                         (const float4*)b2, nullptr, nullptr, nullptr, N);

  // ---- Layer 3 (64 -> 64) + head: input B1, acc B2, head -> out ----
  ptag64_k<true,  false, false><<<g16, 256, 0, stream>>>(ptr, ep, B14, B04, W2k(1,1), W2k(1,0), B24,
                                                         nullptr, nullptr, nullptr, nullptr, N);
  ptag64_k<false, false, false><<<g16, 256, 0, stream>>>(ptr, ep, B04, B14, W2k(1,2), nullptr, B24,
                                                         nullptr, nullptr, nullptr, nullptr, N);
  ptag64_k<false, false, false><<<g16, 256, 0, stream>>>(ptr, ep, B14, B04, W2k(1,3), nullptr, B24,
                                                         nullptr, nullptr, nullptr, nullptr, N);
  ptag64_k<false, true,  true ><<<g16, 256, 0, stream>>>(ptr, ep, B04, nullptr, W2k(1,4), nullptr, B24,
                                                         (const float4*)(b2 + 64), Wout, bout, out, N);
}

// Round 7
// 1212.138 us; speedup vs baseline: 2.5174x; 1.3527x over previous
//
#include <hip/hip_runtime.h>

// ---------------------------------------------------------------------------
// TAGCN node regression: 3 TAGConv layers (K=4) + linear head, fp32 math.
// CSR-by-dst built once per launch (rank from the degree atomic -> fill has
// no atomics). Propagation fused with matmul accumulation; F=64 kernel uses
// 20480 B LDS (8 blocks/CU), R6's 28-VGPR scalar-broadcast mm loop.
// R7: inter-dispatch h stored in BF16 (RNE) -> gather bytes halve (the ~3 TB/s
// TCC plateau is the binding limit; R3->R6 showed occupancy no longer pays).
// All accumulation fp32; only the 12 h stores quantize.
// ---------------------------------------------------------------------------

typedef unsigned long long u64;

__device__ __forceinline__ float bf2f(unsigned short u) {
  return __uint_as_float(((unsigned int)u) << 16);
}
__device__ __forceinline__ unsigned short f2bf(float f) {
  unsigned int u = __float_as_uint(f);
  u += 0x7FFF + ((u >> 16) & 1);  // round to nearest even
  return (unsigned short)(u >> 16);
}
__device__ __forceinline__ ushort4 pack_bf(float4 v) {
  ushort4 r;
  r.x = f2bf(v.x); r.y = f2bf(v.y); r.z = f2bf(v.z); r.w = f2bf(v.w);
  return r;
}

// one 64-bit atomic per edge: [count:16 | sum_w Q16.32 fixed point:48]
__global__ void degcount_k(const int* __restrict__ dst, const float* __restrict__ w,
                           u64* __restrict__ pack, int* __restrict__ rank, int E) {
  int e = blockIdx.x * blockDim.x + threadIdx.x;
  if (e >= E) return;
  int d = dst[e];
  u64 v = ((u64)1 << 48) | (u64)((double)w[e] * 4294967296.0);
  u64 old = atomicAdd(&pack[d], v);
  rank[e] = (int)(old >> 48);
}

// scan (256/block) fused with degree decode -> dinv
__global__ void scan_blocks(const u64* __restrict__ pack, float* __restrict__ dinv,
                            int* __restrict__ ptr, int* __restrict__ bsum, int n) {
  __shared__ int s[256];
  int tid = threadIdx.x;
  int i = blockIdx.x * 256 + tid;
  int v = 0;
  if (i < n) {
    u64 p = pack[i];
    v = (int)(p >> 48);
    float d = (float)((double)(p & 0xFFFFFFFFFFFFULL) * (1.0 / 4294967296.0));
    dinv[i] = (d > 0.f) ? rsqrtf(fmaxf(d, 1e-30f)) : 0.f;
  }
  s[tid] = v;
  __syncthreads();
#pragma unroll
  for (int off = 1; off < 256; off <<= 1) {
    int t = (tid >= off) ? s[tid - off] : 0;
    __syncthreads();
    s[tid] += t;
    __syncthreads();
  }
  if (i < n) ptr[i] = s[tid] - v;
  if (tid == 255) bsum[blockIdx.x] = s[255];
}

__global__ void scan_sums(int* __restrict__ bsum, int nb) {
  __shared__ int s[512];
  int tid = threadIdx.x;
  int v = (tid < nb) ? bsum[tid] : 0;
  s[tid] = v;
  __syncthreads();
#pragma unroll
  for (int off = 1; off < 512; off <<= 1) {
    int t = (tid >= off) ? s[tid - off] : 0;
    __syncthreads();
    s[tid] += t;
    __syncthreads();
  }
  if (tid < nb) bsum[tid] = s[tid] - v;
}

__global__ void scan_add(int* __restrict__ ptr, const int* __restrict__ bsum, int n, int E) {
  int i = blockIdx.x * blockDim.x + threadIdx.x;
  if (i < n) ptr[i] += bsum[i >> 8];
  if (i == 0) ptr[n] = E;
}

// scatter edges into CSR slots (atomic-free); payload = {src, folded norm}
__global__ void fill_k(const int* __restrict__ src, const int* __restrict__ dst,
                       const float* __restrict__ w, const float* __restrict__ dinv,
                       const int* __restrict__ ptr, const int* __restrict__ rank,
                       int2* __restrict__ ep, int E) {
  int e = blockIdx.x * blockDim.x + threadIdx.x;
  if (e >= E) return;
  int s = src[e], d = dst[e];
  float nv = dinv[s] * w[e] * dinv[d];
  int pos = ptr[d] + rank[e];
  ep[pos] = make_int2(s, __float_as_int(nv));
}

// x (fp32, N x 16) -> bf16
__global__ void cvt_k(const float4* __restrict__ x4, ushort4* __restrict__ xb, int n4) {
  int i = blockIdx.x * blockDim.x + threadIdx.x;
  if (i < n4) xb[i] = pack_bf(x4[i]);
}

// gather t[f4] = sum_e w_e * bf2f(hin[src_e][f4]); hin row = F4 ushort4s
template <int F4>
__device__ __forceinline__ float4 gather(const int* __restrict__ ptr, const int2* __restrict__ ep,
                                         const ushort4* __restrict__ hin, int node, int f4) {
  int e0 = ptr[node], e1 = ptr[node + 1];
  float4 a = make_float4(0.f, 0.f, 0.f, 0.f);
  int e = e0;
  if ((e & 1) && e < e1) {
    int2 p = ep[e];
    float w0 = __int_as_float(p.y);
    ushort4 h = hin[(size_t)p.x * F4 + f4];
    a.x = fmaf(w0, bf2f(h.x), a.x); a.y = fmaf(w0, bf2f(h.y), a.y);
    a.z = fmaf(w0, bf2f(h.z), a.z); a.w = fmaf(w0, bf2f(h.w), a.w);
    ++e;
  }
  for (; e + 1 < e1; e += 2) {
    int4 p = *(const int4*)(ep + e);  // 2 edges, 16B aligned
    float w0 = __int_as_float(p.y), w1 = __int_as_float(p.w);
    ushort4 h0 = hin[(size_t)p.x * F4 + f4];
    ushort4 h1 = hin[(size_t)p.z * F4 + f4];
    a.x = fmaf(w0, bf2f(h0.x), a.x); a.y = fmaf(w0, bf2f(h0.y), a.y);
    a.z = fmaf(w0, bf2f(h0.z), a.z); a.w = fmaf(w0, bf2f(h0.w), a.w);
    a.x = fmaf(w1, bf2f(h1.x), a.x); a.y = fmaf(w1, bf2f(h1.y), a.y);
    a.z = fmaf(w1, bf2f(h1.z), a.z); a.w = fmaf(w1, bf2f(h1.w), a.w);
  }
  if (e < e1) {
    int2 p = ep[e];
    float w0 = __int_as_float(p.y);
    ushort4 h = hin[(size_t)p.x * F4 + f4];
    a.x = fmaf(w0, bf2f(h.x), a.x); a.y = fmaf(w0, bf2f(h.y), a.y);
    a.z = fmaf(w0, bf2f(h.z), a.z); a.w = fmaf(w0, bf2f(h.w), a.w);
  }
  return a;
}

// scalar-broadcast mm accumulate: a += t(group ln) @ W  (28-VGPR shape, R6).
// t element i of group ln lives at word ln*64 + (((i>>2)^ln)<<2 | (i&3)).
__device__ __forceinline__ void mm_acc(const float* __restrict__ tl, const float4* __restrict__ Wl,
                                       int ln, int j4, float4& a) {
#pragma unroll 8
  for (int i = 0; i < 64; ++i) {
    float tv = tl[ln * 64 + ((((i >> 2) ^ ln) << 2) | (i & 3))];
    float4 wv = Wl[i * 16 + j4];
    a.x = fmaf(tv, wv.x, a.x); a.y = fmaf(tv, wv.y, a.y);
    a.z = fmaf(tv, wv.z, a.z); a.w = fmaf(tv, wv.w, a.w);
  }
}

// ---------- fused prop + matmul, F=64 (16 lanes/node, 16 nodes/block) ----------
// LDS = 16K W + 4K XOR-swizzled t tile = 20480 B -> 8 blocks/CU (VGPR ~28).
template <bool FIRST, bool LAST, bool HEAD>
__launch_bounds__(256)
__global__ void ptag64_k(const int* __restrict__ ptr, const int2* __restrict__ ep,
                         const ushort4* __restrict__ hin, ushort4* __restrict__ hout,
                         const float4* __restrict__ Wk4, const float4* __restrict__ W04,
                         float4* __restrict__ acc4, const float4* __restrict__ bias4,
                         const float* __restrict__ Wout, const float* __restrict__ bout,
                         float* __restrict__ outv, int n) {
  __shared__ float4 Wl[1024];  // 64x64 weight (reused for W0 in FIRST phase B)
  __shared__ float4 tl4[256];  // t tile, slot = ln*16 + (j4^ln)  (bank-clean)
  const float* tl = (const float*)tl4;
  int tid = threadIdx.x;
  for (int i = tid; i < 1024; i += 256) Wl[i] = Wk4[i];
  int gid = blockIdx.x * 256 + tid;
  int node = gid >> 4, j4 = gid & 15, ln = tid >> 4;

  float4 t = make_float4(0.f, 0.f, 0.f, 0.f);
  if (node < n) {
    t = gather<16>(ptr, ep, hin, node, j4);
    if (!LAST) hout[(size_t)node * 16 + j4] = pack_bf(t);
  }
  tl4[ln * 16 + (j4 ^ ln)] = t;
  __syncthreads();

  float4 a = make_float4(0.f, 0.f, 0.f, 0.f);
  if (!FIRST && node < n) a = acc4[(size_t)node * 16 + j4];
  mm_acc(tl, Wl, ln, j4, a);
  if (FIRST) {  // phase B: own-term h0 @ W0, same LDS buffers
    __syncthreads();
    for (int i = tid; i < 1024; i += 256) Wl[i] = W04[i];
    float4 own = make_float4(0.f, 0.f, 0.f, 0.f);
    if (node < n) {
      ushort4 h = hin[(size_t)node * 16 + j4];
      own = make_float4(bf2f(h.x), bf2f(h.y), bf2f(h.z), bf2f(h.w));
    }
    tl4[ln * 16 + (j4 ^ ln)] = own;
    __syncthreads();
    mm_acc(tl, Wl, ln, j4, a);
  }
  if (node >= n) return;  // no barriers below

  if (LAST) {
    float4 b = bias4[j4];
    a.x += b.x; a.y += b.y; a.z += b.z; a.w += b.w;
    a.x = (a.x >= 0.f) ? a.x : 0.01f * a.x;
    a.y = (a.y >= 0.f) ? a.y : 0.01f * a.y;
    a.z = (a.z >= 0.f) ? a.z : 0.01f * a.z;
    a.w = (a.w >= 0.f) ? a.w : 0.01f * a.w;
    if (HEAD) {
      float v = a.x * Wout[4 * j4] + a.y * Wout[4 * j4 + 1] +
                a.z * Wout[4 * j4 + 2] + a.w * Wout[4 * j4 + 3];
      v += __shfl_down(v, 8, 16);
      v += __shfl_down(v, 4, 16);
      v += __shfl_down(v, 2, 16);
      v += __shfl_down(v, 1, 16);
      if (j4 == 0) outv[node] = v + bout[0];
    } else {
      hout[(size_t)node * 16 + j4] = pack_bf(a);  // activated layer output
    }
  } else {
    acc4[(size_t)node * 16 + j4] = a;
  }
}

// ---------- fused prop + matmul, layer 1: F_in=16 (4 lanes/node, 64 nodes/block) ----------
template <bool FIRST, bool LAST>
__launch_bounds__(256)
__global__ void ptag16_k(const int* __restrict__ ptr, const int2* __restrict__ ep,
                         const ushort4* __restrict__ hin, ushort4* __restrict__ hout,
                         const float4* __restrict__ Wk4, const float4* __restrict__ W04,
                         float4* __restrict__ acc4, const float4* __restrict__ bias4,
                         ushort4* __restrict__ outbuf, int n) {
  __shared__ float4 Wl[256];               // 16x64 W_k
  __shared__ float4 W0l[FIRST ? 256 : 1];  // 16x64 W_0
  __shared__ float4 tl4[64 * 5];           // t tile, stride 5 float4
  const float* tl = (const float*)tl4;
  int tid = threadIdx.x;
  Wl[tid] = Wk4[tid];
  if (FIRST) W0l[tid] = W04[tid];
  int gid = blockIdx.x * 256 + tid;
  int node = gid >> 2, q = tid & 3, ln = tid >> 2;

  float4 t = make_float4(0.f, 0.f, 0.f, 0.f);
  if (node < n) {
    t = gather<4>(ptr, ep, hin, node, q);
    if (!LAST) hout[(size_t)node * 4 + q] = pack_bf(t);
  }
  tl4[ln * 5 + q] = t;
  __syncthreads();

  float4 a[4];
#pragma unroll
  for (int c = 0; c < 4; ++c) a[c] = make_float4(0.f, 0.f, 0.f, 0.f);
  if (!FIRST && node < n) {
#pragma unroll
    for (int c = 0; c < 4; ++c) a[c] = acc4[(size_t)node * 16 + 4 * q + c];
  }
#pragma unroll 4
  for (int i = 0; i < 16; ++i) {
    float tv = tl[ln * 20 + i];
#pragma unroll
    for (int c = 0; c < 4; ++c) {
      float4 wv = Wl[i * 16 + 4 * q + c];
      a[c].x = fmaf(tv, wv.x, a[c].x); a[c].y = fmaf(tv, wv.y, a[c].y);
      a[c].z = fmaf(tv, wv.z, a[c].z); a[c].w = fmaf(tv, wv.w, a[c].w);
    }
  }
  if (FIRST) {  // own-term x @ W0
    __syncthreads();
    float4 own = make_float4(0.f, 0.f, 0.f, 0.f);
    if (node < n) {
      ushort4 h = hin[(size_t)node * 4 + q];
      own = make_float4(bf2f(h.x), bf2f(h.y), bf2f(h.z), bf2f(h.w));
    }
    tl4[ln * 5 + q] = own;
    __syncthreads();
#pragma unroll 4
    for (int i = 0; i < 16; ++i) {
      float tv = tl[ln * 20 + i];
#pragma unroll
      for (int c = 0; c < 4; ++c) {
        float4 wv = W0l[i * 16 + 4 * q + c];
        a[c].x = fmaf(tv, wv.x, a[c].x); a[c].y = fmaf(tv, wv.y, a[c].y);
        a[c].z = fmaf(tv, wv.z, a[c].z); a[c].w = fmaf(tv, wv.w, a[c].w);
      }
    }
  }
  if (node >= n) return;

  if (LAST) {
#pragma unroll
    for (int c = 0; c < 4; ++c) {
      float4 b = bias4[4 * q + c];
      a[c].x += b.x; a[c].y += b.y; a[c].z += b.z; a[c].w += b.w;
      a[c].x = (a[c].x >= 0.f) ? a[c].x : 0.01f * a[c].x;
      a[c].y = (a[c].y >= 0.f) ? a[c].y : 0.01f * a[c].y;
      a[c].z = (a[c].z >= 0.f) ? a[c].z : 0.01f * a[c].z;
      a[c].w = (a[c].w >= 0.f) ? a[c].w : 0.01f * a[c].w;
      outbuf[(size_t)node * 16 + 4 * q + c] = pack_bf(a[c]);  // activated h1, bf16
    }
  } else {
#pragma unroll
    for (int c = 0; c < 4; ++c) acc4[(size_t)node * 16 + 4 * q + c] = a[c];
  }
}

extern "C" void kernel_launch(void* const* d_in, const int* in_sizes, int n_in,
                              void* d_out, int out_size, void* d_ws, size_t ws_size,
                              hipStream_t stream) {
  const float* x    = (const float*)d_in[0];
  const int*   ei   = (const int*)d_in[1];
  const float* ew   = (const float*)d_in[2];
  const float* W1   = (const float*)d_in[4];
  const float* b1   = (const float*)d_in[5];
  const float* W2   = (const float*)d_in[6];
  const float* b2   = (const float*)d_in[7];
  const float* Wout = (const float*)d_in[8];
  const float* bout = (const float*)d_in[9];
  float* out = (float*)d_out;

  const int N = in_sizes[0] / 16;
  const int E = in_sizes[2];
  const int* src = ei;
  const int* dst = ei + E;

  char* ws = (char*)d_ws;
  size_t off = 0;
  auto alloc = [&](size_t bytes) {
    char* p = ws + off;
    off = (off + bytes + 255) & ~(size_t)255;
    return p;
  };
  u64*     pack = (u64*)alloc((size_t)N * 8);
  float*   dinv = (float*)alloc((size_t)N * 4);
  int*     ptr  = (int*)alloc(((size_t)N + 1) * 4);
  int*     bsum = (int*)alloc(4096);
  int*     rank = (int*)alloc((size_t)E * 4);
  int2*    ep   = (int2*)alloc((size_t)E * 8);
  ushort4* xb   = (ushort4*)alloc((size_t)N * 16 * 2);       // N x 16 bf16
  ushort4* hb0  = (ushort4*)alloc((size_t)N * 64 * 2);       // t ping
  ushort4* hb1  = (ushort4*)alloc((size_t)N * 64 * 2);       // t pong
  ushort4* hb2  = (ushort4*)alloc((size_t)N * 64 * 2);       // layer outputs
  float4*  accf = (float4*)alloc((size_t)N * 64 * 4);        // fp32 acc

  hipMemsetAsync(pack, 0, (size_t)N * 8, stream);

  int gE = (E + 255) / 256;
  int gN = (N + 255) / 256;
  degcount_k<<<gE, 256, 0, stream>>>(dst, ew, pack, rank, E);
  scan_blocks<<<gN, 256, 0, stream>>>(pack, dinv, ptr, bsum, N);
  scan_sums<<<1, 512, 0, stream>>>(bsum, gN);
  scan_add<<<gN, 256, 0, stream>>>(ptr, bsum, N, E);
  fill_k<<<gE, 256, 0, stream>>>(src, dst, ew, dinv, ptr, rank, ep, E);
  cvt_k<<<(N * 4 + 255) / 256, 256, 0, stream>>>((const float4*)x, xb, N * 4);

  int g4  = (N * 4 + 255) / 256;   // layer-1 fused (4 lanes/node)
  int g16 = (N * 16 + 255) / 256;  // F=64 fused (16 lanes/node)

  auto W1k = [&](int k) { return (const float4*)(W1 + (size_t)k * 1024); };
  auto W2k = [&](int l, int k) { return (const float4*)(W2 + ((size_t)l * 5 + k) * 4096); };

  // ---- Layer 1 (16 -> 64): acc in accf, t ping-pong hb0/hb1 (stride 4), h1 -> hb2 ----
  ptag16_k<true,  false><<<g4, 256, 0, stream>>>(ptr, ep, xb,  hb0, W1k(1), W1k(0), accf, nullptr, nullptr, N);
  ptag16_k<false, false><<<g4, 256, 0, stream>>>(ptr, ep, hb0, hb1, W1k(2), nullptr, accf, nullptr, nullptr, N);
  ptag16_k<false, false><<<g4, 256, 0, stream>>>(ptr, ep, hb1, hb0, W1k(3), nullptr, accf, nullptr, nullptr, N);
  ptag16_k<false, true ><<<g4, 256, 0, stream>>>(ptr, ep, hb0, nullptr, W1k(4), nullptr, accf,
                                                 (const float4*)b1, hb2, N);

  // ---- Layer 2 (64 -> 64): input hb2, t ping-pong hb0/hb1, h2 -> hb2 ----
  ptag64_k<true,  false, false><<<g16, 256, 0, stream>>>(ptr, ep, hb2, hb0, W2k(0,1), W2k(0,0), accf,
                                                         nullptr, nullptr, nullptr, nullptr, N);
  ptag64_k<false, false, false><<<g16, 256, 0, stream>>>(ptr, ep, hb0, hb1, W2k(0,2), nullptr, accf,
                                                         nullptr, nullptr, nullptr, nullptr, N);
  ptag64_k<false, false, false><<<g16, 256, 0, stream>>>(ptr, ep, hb1, hb0, W2k(0,3), nullptr, accf,
                                                         nullptr, nullptr, nullptr, nullptr, N);
  ptag64_k<false, true,  false><<<g16, 256, 0, stream>>>(ptr, ep, hb0, hb2, W2k(0,4), nullptr, accf,
                                                         (const float4*)b2, nullptr, nullptr, nullptr, N);

  // ---- Layer 3 (64 -> 64) + head: input hb2, head -> out ----
  ptag64_k<true,  false, false><<<g16, 256, 0, stream>>>(ptr, ep, hb2, hb0, W2k(1,1), W2k(1,0), accf,
                                                         nullptr, nullptr, nullptr, nullptr, N);
  ptag64_k<false, false, false><<<g16, 256, 0, stream>>>(ptr, ep, hb0, hb1, W2k(1,2), nullptr, accf,
                                                         nullptr, nullptr, nullptr, nullptr, N);
  ptag64_k<false, false, false><<<g16, 256, 0, stream>>>(ptr, ep, hb1, hb0, W2k(1,3), nullptr, accf,
                                                         nullptr, nullptr, nullptr, nullptr, N);
  ptag64_k<false, true,  true ><<<g16, 256, 0, stream>>>(ptr, ep, hb0, nullptr, W2k(1,4), nullptr, accf,
                                                         (const float4*)(b2 + 64), Wout, bout, out, N);
}